// Round 1
// baseline (912.263 us; speedup 1.0000x reference)
//
#include <hip/hip_runtime.h>

// Problem constants (match reference)
#define Bdim 8
#define Tdim 1024
#define Ndim 64
#define Kdim 8
// log_a: ((b*T + t)*N + n)*64 + i*8 + j    (stride over t: N*64 = 4096)
// log_b / fwd / bwd / g1: ((b*T + t)*N + n)*8 + k   (stride over t: N*8 = 512)
// gamma2: ((b*T + t)*N + n)*64 + i*8 + j

#define FSZ (Bdim * Tdim * Ndim * Kdim)        // 4194304

// ---------------- forward kernel ----------------
// One wave (64 threads) per (b,n) chain. lane = i*8+j.
// State alpha is j-indexed (lane holds alpha[lane&7], replicated across i-groups).

__device__ __forceinline__ void fwd_load(const float* __restrict__ a_base,
                                         const float* __restrict__ b_base,
                                         int t0, int lane,
                                         float (&ab)[16], float (&bb)[2]) {
#pragma unroll
  for (int s = 0; s < 16; ++s) {
    int t = t0 + s; if (t > Tdim - 1) t = Tdim - 1;
    ab[s] = a_base[(size_t)t * (Ndim * 64) + lane];
  }
#pragma unroll
  for (int h = 0; h < 2; ++h) {
    int t = t0 + h * 8 + (lane >> 3); if (t > Tdim - 1) t = Tdim - 1;
    bb[h] = b_base[(size_t)t * (Ndim * 8) + (lane & 7)];
  }
}

__device__ __forceinline__ void fwd_compute(int t0, int lane,
                                            const float (&ab)[16], const float (&bb)[2],
                                            float& alpha, float* __restrict__ f_base) {
  const int i = lane >> 3;
#pragma unroll
  for (int s = 0; s < 16; ++s) {
    int t = t0 + s;
    if (t < Tdim) {
      // b[t][i] broadcast from batch register
      float bi = __shfl(bb[s >> 3], ((s & 7) << 3) + i, 64);
      float v = bi + ab[s] + alpha;          // b_t[i] + a_t[i,j] + alpha_{t-1}[j]
      float p = __expf(v);                   // no-max logsumexp: v in safe range
      float Si = p;                          // sum over j (within i-group)
      Si += __shfl_xor(Si, 1, 64);
      Si += __shfl_xor(Si, 2, 64);
      Si += __shfl_xor(Si, 4, 64);
      float Tt = Si;                         // sum over i (across groups)
      Tt += __shfl_xor(Tt, 8, 64);
      Tt += __shfl_xor(Tt, 16, 64);
      Tt += __shfl_xor(Tt, 32, 64);
      float ai = __logf(Si) - __logf(Tt);    // alpha_t[i], i-indexed, replicated
      if ((lane & 7) == 0) f_base[(size_t)t * (Ndim * 8) + i] = ai;  // 32B coalesced
      alpha = __shfl(ai, (lane & 7) << 3, 64);  // transpose -> j-indexed
    }
  }
}

__global__ __launch_bounds__(64) void fwd_kernel(const float* __restrict__ A,
                                                 const float* __restrict__ Bm,
                                                 const float* __restrict__ Z1,
                                                 float* __restrict__ Fout) {
  const int chain = blockIdx.x;          // 0..511
  const int b = chain >> 6, n = chain & 63;
  const int lane = threadIdx.x;
  const int j = lane & 7;
  const size_t cbase = ((size_t)b * Tdim) * Ndim + n;
  const float* a_base = A + cbase * 64;
  const float* b_base = Bm + cbase * 8;
  float* f_base = Fout + cbase * 8;

  // t = 0: alpha0 = normalize(z1[n] + b[b,0,n], over k)
  float v0 = Z1[n * 8 + j] + b_base[j];
  float s0 = __expf(v0);
  s0 += __shfl_xor(s0, 1, 64);
  s0 += __shfl_xor(s0, 2, 64);
  s0 += __shfl_xor(s0, 4, 64);
  float alpha = v0 - __logf(s0);           // j-indexed
  if (lane < 8) f_base[lane] = alpha;

  float A0[16], A1[16], B0[2], B1[2];
  fwd_load(a_base, b_base, 1, lane, A0, B0);
#pragma unroll 1
  for (int kk = 0; kk < 64; kk += 2) {
    fwd_load(a_base, b_base, 1 + (kk + 1) * 16, lane, A1, B1);
    fwd_compute(1 + kk * 16, lane, A0, B0, alpha, f_base);
    if (kk + 2 < 64) fwd_load(a_base, b_base, 1 + (kk + 2) * 16, lane, A0, B0);
    fwd_compute(1 + (kk + 1) * 16, lane, A1, B1, alpha, f_base);
  }
}

// ---------------- backward + gamma kernel ----------------
// State beta is i-indexed. Per step t (from T-1 down to 1):
//   v = beta_t[i] + a_t[i,j] + b_t[i];  V_j = sum_i e^v;  W = sum_j V_j
//   Q_j = e^{alpha_{t-1}[j]} * V_j;     Qt = sum_j Q_j
//   beta_{t-1}[j] = ln V_j - ln W
//   gamma2[t]     = v + alpha_{t-1}[j] - ln Qt
//   gamma1[t-1]   = alpha_{t-1}[j] + ln V_j - ln Qt

__device__ __forceinline__ void bwd_load(const float* __restrict__ a_base,
                                         const float* __restrict__ b_base,
                                         const float* __restrict__ f_base,
                                         int t0, int lane,
                                         float (&ab)[16], float (&bb)[2], float (&al)[2]) {
#pragma unroll
  for (int s = 0; s < 16; ++s) {
    int t = t0 - s;                         // always >= 0
    ab[s] = a_base[(size_t)t * (Ndim * 64) + lane];
  }
#pragma unroll
  for (int h = 0; h < 2; ++h) {
    int t = t0 - (h * 8 + (lane >> 3));     // >= 0
    bb[h] = b_base[(size_t)t * (Ndim * 8) + (lane & 7)];
    int ta = t - 1; if (ta < 0) ta = 0;     // alpha[t-1]; t=0 step is skipped anyway
    al[h] = f_base[(size_t)ta * (Ndim * 8) + (lane & 7)];
  }
}

__device__ __forceinline__ void bwd_compute(int t0, int lane,
                                            const float (&ab)[16], const float (&bb)[2],
                                            const float (&al)[2],
                                            float& beta_i,
                                            float* __restrict__ bo,
                                            float* __restrict__ g1,
                                            float* __restrict__ g2) {
  const int i = lane >> 3, j = lane & 7;
#pragma unroll
  for (int s = 0; s < 16; ++s) {
    int t = t0 - s;
    if (t >= 1) {
      float bi = __shfl(bb[s >> 3], ((s & 7) << 3) + i, 64);
      float aj = __shfl(al[s >> 3], ((s & 7) << 3) + j, 64);  // alpha[t-1][j]
      float v = beta_i + ab[s] + bi;
      float p = __expf(v);
      float Vj = p;                           // sum over i
      Vj += __shfl_xor(Vj, 8, 64);
      Vj += __shfl_xor(Vj, 16, 64);
      Vj += __shfl_xor(Vj, 32, 64);
      float ea = __expf(aj);
      float Qj = Vj * ea;
      float W = Vj;                           // sum over j
      W += __shfl_xor(W, 1, 64);
      W += __shfl_xor(W, 2, 64);
      W += __shfl_xor(W, 4, 64);
      float Qt = Qj;                          // sum over j
      Qt += __shfl_xor(Qt, 1, 64);
      Qt += __shfl_xor(Qt, 2, 64);
      Qt += __shfl_xor(Qt, 4, 64);
      float lnV = __logf(Vj);
      float lnW = __logf(W);
      float lnQ = __logf(Qt);
      float beta_new = lnV - lnW;             // beta[t-1], j-indexed
      g2[(size_t)t * (Ndim * 64) + lane] = v + aj - lnQ;   // 256B coalesced
      if (lane < 8) {
        bo[(size_t)(t - 1) * (Ndim * 8) + lane] = beta_new;
        g1[(size_t)(t - 1) * (Ndim * 8) + lane] = aj + lnV - lnQ;
      }
      beta_i = __shfl(beta_new, i, 64);       // transpose -> i-indexed
    }
  }
}

__global__ __launch_bounds__(64) void bwd_kernel(const float* __restrict__ A,
                                                 const float* __restrict__ Bm,
                                                 const float* __restrict__ Fwd,
                                                 float* __restrict__ Bout,
                                                 float* __restrict__ G1,
                                                 float* __restrict__ G2) {
  const int chain = blockIdx.x;
  const int b = chain >> 6, n = chain & 63;
  const int lane = threadIdx.x;
  const size_t cbase = ((size_t)b * Tdim) * Ndim + n;
  const float* a_base = A + cbase * 64;
  const float* b_base = Bm + cbase * 8;
  const float* f_base = Fwd + cbase * 8;
  float* bo = Bout + cbase * 8;
  float* g1 = G1 + cbase * 8;
  float* g2 = G2 + cbase * 64;

  // t = T-1: beta = 0; gamma1[T-1] = normalize(alpha[T-1])
  float aT = f_base[(size_t)(Tdim - 1) * (Ndim * 8) + (lane & 7)];
  float eT = __expf(aT);
  eT += __shfl_xor(eT, 1, 64);
  eT += __shfl_xor(eT, 2, 64);
  eT += __shfl_xor(eT, 4, 64);
  float gT = aT - __logf(eT);
  if (lane < 8) {
    bo[(size_t)(Tdim - 1) * (Ndim * 8) + lane] = 0.f;
    g1[(size_t)(Tdim - 1) * (Ndim * 8) + lane] = gT;
  }
  float beta_i = 0.f;

  float A0[16], A1[16], B0[2], B1[2], L0[2], L1[2];
  bwd_load(a_base, b_base, f_base, Tdim - 1, lane, A0, B0, L0);
#pragma unroll 1
  for (int kk = 0; kk < 64; kk += 2) {
    bwd_load(a_base, b_base, f_base, Tdim - 1 - (kk + 1) * 16, lane, A1, B1, L1);
    bwd_compute(Tdim - 1 - kk * 16, lane, A0, B0, L0, beta_i, bo, g1, g2);
    if (kk + 2 < 64)
      bwd_load(a_base, b_base, f_base, Tdim - 1 - (kk + 2) * 16, lane, A0, B0, L0);
    bwd_compute(Tdim - 1 - (kk + 1) * 16, lane, A1, B1, L1, beta_i, bo, g1, g2);
  }

  // gamma2[:, 0] = 0
  g2[lane] = 0.f;
}

extern "C" void kernel_launch(void* const* d_in, const int* in_sizes, int n_in,
                              void* d_out, int out_size, void* d_ws, size_t ws_size,
                              hipStream_t stream) {
  const float* A  = (const float*)d_in[0];   // (B,T,N,K,K)
  const float* Bm = (const float*)d_in[1];   // (B,T,N,K)
  const float* Z1 = (const float*)d_in[2];   // (N,K)
  float* out = (float*)d_out;
  float* Fout = out;                // forward_probs
  float* Bout = out + FSZ;          // backward_probs
  float* G1   = out + 2 * FSZ;      // gamma1
  float* G2   = out + 3 * FSZ;      // gamma2

  fwd_kernel<<<dim3(Bdim * Ndim), dim3(64), 0, stream>>>(A, Bm, Z1, Fout);
  bwd_kernel<<<dim3(Bdim * Ndim), dim3(64), 0, stream>>>(A, Bm, Fout, Bout, G1, G2);
}

// Round 2
// 687.348 us; speedup vs baseline: 1.3272x; 1.3272x over previous
//
#include <hip/hip_runtime.h>

#define Tdim 1024
#define Ndim 64
#define FSZ (8 * 1024 * 64 * 8)

#define XSUM_GRP(v)   { v += __shfl_xor(v, 1, 64); v += __shfl_xor(v, 2, 64); v += __shfl_xor(v, 4, 64); }
#define XSUM_CROSS(v) { v += __shfl_xor(v, 8, 64); v += __shfl_xor(v, 16, 64); v += __shfl_xor(v, 32, 64); }

// ---------------- kernel 1: forward + beta recursions ----------------
// One wave per chain. lane = x*8+y. Probability-domain state, alternating
// index layout (odd t: normal A load, in-group reduce; even t: transposed A
// load, cross-group reduce) -> no transpose shuffle in the chain.
// Chain per step: mul -> 3 shfl-add -> mul. exp/log/rcp all off-chain.

__device__ __forceinline__ void fwd_load(const float* __restrict__ a_base,
                                         const float* __restrict__ b_base,
                                         int t0, int lane, int tr, int x, int y,
                                         float (&ea)[16], float (&bb)[2]) {
#pragma unroll
  for (int s = 0; s < 16; ++s) {
    int t = t0 + s; if (t > Tdim - 1) t = Tdim - 1;
    ea[s] = __expf(a_base[(size_t)t * (Ndim * 64) + ((s & 1) ? tr : lane)]);
  }
#pragma unroll
  for (int h = 0; h < 2; ++h) {
    int t = t0 + h * 8 + x; if (t > Tdim - 1) t = Tdim - 1;
    bb[h] = b_base[(size_t)t * (Ndim * 8) + y];
  }
}

__device__ __forceinline__ void fwd_compute(int t0, int x, int y,
                                            const float (&ea)[16], const float (&bb)[2],
                                            float& q, float& sc,
                                            float* __restrict__ f_base) {
#pragma unroll
  for (int s = 0; s < 16; ++s) {
    int t = t0 + s;
    if (t < Tdim) {
      int oidx = (s & 1) ? y : x;                       // output state index role
      float bi = __shfl(bb[s >> 3], ((s & 7) << 3) | oidx, 64);  // b_t[i], off-chain
      float ws = __expf(bi) * sc;                       // off-chain (sc = 1/T_prev)
      float v = ea[s] * q;                              // CHAIN
      if (!(s & 1)) { XSUM_GRP(v); } else { XSUM_CROSS(v); }  // CHAIN: sum over j
      float S = v * ws;                                 // CHAIN
      q = S;
      float T = S;                                      // off-chain from here
      if (!(s & 1)) { XSUM_CROSS(T); } else { XSUM_GRP(T); }
      sc = 1.0f / T;
      float la = __logf(S) - __logf(T);                 // normalized alpha (scale cancels)
      if ((((s & 1) ? x : y)) == 0) f_base[(size_t)t * (Ndim * 8) + oidx] = la;
    }
  }
}

// beta: u_i ~ e^{beta_tau[i] + b_tau[i]} (scaled). r_j = sum_i e^{a_tau[i,j]} u_i.
// beta_{tau-1}[j] = ln r_j - ln W,  u' = e^{b_{tau-1}} * r * sc.
__device__ __forceinline__ void bwd_load(const float* __restrict__ a_base,
                                         const float* __restrict__ b_base,
                                         int t0, int lane, int tr, int x, int y,
                                         float (&ea)[16], float (&bb)[2]) {
#pragma unroll
  for (int s = 0; s < 16; ++s) {
    int t = t0 - s; if (t < 0) t = 0;
    ea[s] = __expf(a_base[(size_t)t * (Ndim * 64) + ((s & 1) ? tr : lane)]);
  }
#pragma unroll
  for (int h = 0; h < 2; ++h) {
    int t = t0 - 1 - (h * 8 + x); if (t < 0) t = 0;    // b at time tau-1
    bb[h] = b_base[(size_t)t * (Ndim * 8) + y];
  }
}

__device__ __forceinline__ void bwd_compute(int t0, int x, int y,
                                            const float (&ea)[16], const float (&bb)[2],
                                            float& u, float& sc,
                                            float* __restrict__ bo) {
#pragma unroll
  for (int s = 0; s < 16; ++s) {
    int tau = t0 - s;
    if (tau >= 1) {
      float v = ea[s] * u;                              // CHAIN
      if (!(s & 1)) { XSUM_CROSS(v); } else { XSUM_GRP(v); }  // CHAIN: sum over i
      int oidx = (s & 1) ? x : y;                       // r's index role
      float bi = __shfl(bb[s >> 3], ((s & 7) << 3) | oidx, 64);  // b_{tau-1}, off-chain
      float unew = __expf(bi) * sc * v;                 // CHAIN tail (ebi*sc hoisted)
      float W = v;                                      // off-chain
      if (!(s & 1)) { XSUM_GRP(W); } else { XSUM_CROSS(W); }
      float lb = __logf(v) - __logf(W);
      if ((((s & 1) ? y : x)) == 0) bo[(size_t)(tau - 1) * (Ndim * 8) + oidx] = lb;
      u = unew;
      sc = 1.0f / W;
    }
  }
}

__global__ __launch_bounds__(64) void chains_kernel(const float* __restrict__ A,
                                                    const float* __restrict__ Bm,
                                                    const float* __restrict__ Z1,
                                                    float* __restrict__ Fout,
                                                    float* __restrict__ Bout) {
  const int lane = threadIdx.x;
  const int x = lane >> 3, y = lane & 7;
  const int tr = (y << 3) | x;
  const int chain = blockIdx.x & 511;
  const int b = chain >> 6, n = chain & 63;
  const size_t cbase = ((size_t)b * Tdim) * Ndim + n;
  const float* a_base = A + cbase * 64;
  const float* b_base = Bm + cbase * 8;

  float ea0[16], ea1[16], bb0[2], bb1[2];

  if (blockIdx.x < 512) {
    // ---- forward chain ----
    float* f_base = Fout + cbase * 8;
    float v0 = Z1[n * 8 + y] + b_base[y];
    float q = __expf(v0);                 // y(=j)-indexed, replicated across groups
    float T0 = q; XSUM_GRP(T0);
    if (x == 0) f_base[y] = v0 - __logf(T0);
    float sc = 1.0f / T0;
    fwd_load(a_base, b_base, 1, lane, tr, x, y, ea0, bb0);
#pragma unroll 1
    for (int kk = 0; kk < 64; kk += 2) {
      fwd_load(a_base, b_base, 1 + (kk + 1) * 16, lane, tr, x, y, ea1, bb1);
      fwd_compute(1 + kk * 16, x, y, ea0, bb0, q, sc, f_base);
      if (kk + 2 < 64) fwd_load(a_base, b_base, 1 + (kk + 2) * 16, lane, tr, x, y, ea0, bb0);
      fwd_compute(1 + (kk + 1) * 16, x, y, ea1, bb1, q, sc, f_base);
    }
  } else {
    // ---- backward (beta) chain ----
    float* bo = Bout + cbase * 8;
    float bT = b_base[(size_t)(Tdim - 1) * (Ndim * 8) + x];
    float u = __expf(bT);                 // x(=i)-indexed (beta_{T-1}=0)
    if (x == 0) bo[(size_t)(Tdim - 1) * (Ndim * 8) + y] = 0.f;
    float sc = 1.0f;
    bwd_load(a_base, b_base, Tdim - 1, lane, tr, x, y, ea0, bb0);
#pragma unroll 1
    for (int kk = 0; kk < 64; kk += 2) {
      bwd_load(a_base, b_base, Tdim - 1 - (kk + 1) * 16, lane, tr, x, y, ea1, bb1);
      bwd_compute(Tdim - 1 - kk * 16, x, y, ea0, bb0, u, sc, bo);
      if (kk + 2 < 64) bwd_load(a_base, b_base, Tdim - 1 - (kk + 2) * 16, lane, tr, x, y, ea0, bb0);
      bwd_compute(Tdim - 1 - (kk + 1) * 16, x, y, ea1, bb1, u, sc, bo);
    }
  }
}

// ---------------- kernel 2: gammas (massively parallel, memory-bound) ----------------
// One 64-lane group per (b,t,n). g1[t] = normalize(F[t]+Bo[t]).
// g2[t] (t>=1) = F[t-1][j] + Bo[t][i] + a[t][i,j] + b[t][i] - lse64(.)
__global__ __launch_bounds__(256) void gamma_kernel(const float* __restrict__ A,
                                                    const float* __restrict__ Bm,
                                                    const float* __restrict__ F,
                                                    const float* __restrict__ Bo,
                                                    float* __restrict__ G1,
                                                    float* __restrict__ G2) {
  const int g = blockIdx.x * 4 + (threadIdx.x >> 6);   // flat (b*T+t)*N+n
  const int lane = threadIdx.x & 63;
  const int x = lane >> 3, y = lane & 7;
  const int t = (g >> 6) & (Tdim - 1);

  // gamma1
  float fy = F[(size_t)g * 8 + y];
  float boy = Bo[(size_t)g * 8 + y];
  float u1 = fy + boy;
  float e1 = __expf(u1);
  float s1 = e1; XSUM_GRP(s1);
  if (x == 0) G1[(size_t)g * 8 + y] = u1 - __logf(s1);

  // gamma2
  if (t == 0) {
    G2[(size_t)g * 64 + lane] = 0.f;
  } else {
    float a = A[(size_t)g * 64 + lane];
    float bi = Bm[(size_t)g * 8 + x];
    float boi = Bo[(size_t)g * 8 + x];
    float fprev = F[((size_t)g - Ndim) * 8 + y];
    float v2 = boi + a + bi + fprev;
    float e2 = __expf(v2);
    float Q = e2; XSUM_GRP(Q); XSUM_CROSS(Q);
    G2[(size_t)g * 64 + lane] = v2 - __logf(Q);
  }
}

extern "C" void kernel_launch(void* const* d_in, const int* in_sizes, int n_in,
                              void* d_out, int out_size, void* d_ws, size_t ws_size,
                              hipStream_t stream) {
  const float* A  = (const float*)d_in[0];   // (B,T,N,K,K)
  const float* Bm = (const float*)d_in[1];   // (B,T,N,K)
  const float* Z1 = (const float*)d_in[2];   // (N,K)
  float* out = (float*)d_out;
  float* Fout = out;                // forward_probs
  float* Bout = out + FSZ;          // backward_probs
  float* G1   = out + 2 * FSZ;      // gamma1
  float* G2   = out + 3 * FSZ;      // gamma2

  chains_kernel<<<dim3(1024), dim3(64), 0, stream>>>(A, Bm, Z1, Fout, Bout);
  gamma_kernel<<<dim3(8 * Tdim * Ndim / 4), dim3(256), 0, stream>>>(A, Bm, Fout, Bout, G1, G2);
}